// Round 1
// baseline (301.625 us; speedup 1.0000x reference)
//
#include <hip/hip_runtime.h>
#include <math.h>

// Problem constants (fixed by setup_inputs)
#define B   4096
#define D   1024
#define C   10000
#define SCALE_F  30.0f
#define LAMBDA_F 0.1f
#define EPS_F    1e-6f
#define LOG2E    1.4426950408889634f
#define NEG_BIG  (-3.402823466e38f)

// Combine two (max, sum-of-exp) partial logsumexp states (natural-exp sums,
// computed via exp2(x*log2e)).
__device__ inline void lse_combine(float& m, float& s, float m2, float s2) {
    float mn = fmaxf(m, m2);
    s = s * exp2f((m - mn) * LOG2E) + s2 * exp2f((m2 - mn) * LOG2E);
    m = mn;
}

// ---------------------------------------------------------------------------
// Kernel 1: cross-entropy rows.  One block per row of outputs [2B, C].
// loss_row = logsumexp(SCALE*row) - SCALE*row[label]; atomicAdd into ws[0].
// ---------------------------------------------------------------------------
__global__ __launch_bounds__(256) void ce_kernel(const float* __restrict__ outputs,
                                                 const int* __restrict__ labels_a,
                                                 const int* __restrict__ labels_n,
                                                 float* __restrict__ acc) {
    const int row = blockIdx.x;          // 0 .. 2B-1
    const int tid = threadIdx.x;
    const int lab = (row < B) ? labels_a[row] : labels_n[row - B];

    const float* rowbase = outputs + (size_t)row * C;
    const float4* rowp = (const float4*)rowbase;
    const float target = rowbase[lab];   // broadcast load (same addr all lanes)

    float m = NEG_BIG, s = 0.0f;
    #pragma unroll 2
    for (int i = tid; i < C / 4; i += 256) {
        float4 v = rowp[i];
        float y0 = SCALE_F * v.x, y1 = SCALE_F * v.y;
        float y2 = SCALE_F * v.z, y3 = SCALE_F * v.w;
        float mloc = fmaxf(fmaxf(y0, y1), fmaxf(y2, y3));
        float mn = fmaxf(m, mloc);
        float sc = exp2f((m - mn) * LOG2E);
        float e = exp2f((y0 - mn) * LOG2E) + exp2f((y1 - mn) * LOG2E)
                + exp2f((y2 - mn) * LOG2E) + exp2f((y3 - mn) * LOG2E);
        s = fmaf(s, sc, e);
        m = mn;
    }

    // wave (64-lane) butterfly reduce
    #pragma unroll
    for (int off = 1; off < 64; off <<= 1) {
        float m2 = __shfl_xor(m, off, 64);
        float s2 = __shfl_xor(s, off, 64);
        lse_combine(m, s, m2, s2);
    }

    __shared__ float sm_m[4], sm_s[4];
    const int wid = tid >> 6, lane = tid & 63;
    if (lane == 0) { sm_m[wid] = m; sm_s[wid] = s; }
    __syncthreads();
    if (tid == 0) {
        float M = sm_m[0], S = sm_s[0];
        lse_combine(M, S, sm_m[1], sm_s[1]);
        lse_combine(M, S, sm_m[2], sm_s[2]);
        lse_combine(M, S, sm_m[3], sm_s[3]);
        float lse = M + log2f(S) / LOG2E;          // natural-log logsumexp
        atomicAdd(acc, lse - SCALE_F * target);
    }
}

// ---------------------------------------------------------------------------
// Kernel 2: exemplar-center term.  One block per batch row.
// hinge = relu(d_ref1 - d_neg1) + relu(d_neg2 - d_ref2); atomicAdd ws[1].
// ---------------------------------------------------------------------------
__global__ __launch_bounds__(256) void center_kernel(const float* __restrict__ anchor,
                                                     const float* __restrict__ negative,
                                                     const float* __restrict__ exemplars,
                                                     const int* __restrict__ labels_a,
                                                     const int* __restrict__ labels_n,
                                                     float* __restrict__ acc) {
    const int row = blockIdx.x;          // 0 .. B-1
    const int tid = threadIdx.x;         // D/4 = 256 float4 per row
    const int la = labels_a[row];
    const int ln = labels_n[row];

    float4 a  = ((const float4*)(anchor    + (size_t)row * D))[tid];
    float4 n  = ((const float4*)(negative  + (size_t)row * D))[tid];
    float4 ea = ((const float4*)(exemplars + (size_t)la  * D))[tid];
    float4 en = ((const float4*)(exemplars + (size_t)ln  * D))[tid];

    // s1=d_ref1(a,ea) s2=d_neg1(n,ea) s3=d_ref2(a,en) s4=d_neg2(n,en)
    float s1 = fabsf(a.x - ea.x + EPS_F) + fabsf(a.y - ea.y + EPS_F)
             + fabsf(a.z - ea.z + EPS_F) + fabsf(a.w - ea.w + EPS_F);
    float s2 = fabsf(n.x - ea.x + EPS_F) + fabsf(n.y - ea.y + EPS_F)
             + fabsf(n.z - ea.z + EPS_F) + fabsf(n.w - ea.w + EPS_F);
    float s3 = fabsf(a.x - en.x + EPS_F) + fabsf(a.y - en.y + EPS_F)
             + fabsf(a.z - en.z + EPS_F) + fabsf(a.w - en.w + EPS_F);
    float s4 = fabsf(n.x - en.x + EPS_F) + fabsf(n.y - en.y + EPS_F)
             + fabsf(n.z - en.z + EPS_F) + fabsf(n.w - en.w + EPS_F);

    #pragma unroll
    for (int off = 1; off < 64; off <<= 1) {
        s1 += __shfl_xor(s1, off, 64);
        s2 += __shfl_xor(s2, off, 64);
        s3 += __shfl_xor(s3, off, 64);
        s4 += __shfl_xor(s4, off, 64);
    }

    __shared__ float sm[4][4];
    const int wid = tid >> 6, lane = tid & 63;
    if (lane == 0) { sm[wid][0] = s1; sm[wid][1] = s2; sm[wid][2] = s3; sm[wid][3] = s4; }
    __syncthreads();
    if (tid == 0) {
        float t1 = sm[0][0] + sm[1][0] + sm[2][0] + sm[3][0];
        float t2 = sm[0][1] + sm[1][1] + sm[2][1] + sm[3][1];
        float t3 = sm[0][2] + sm[1][2] + sm[2][2] + sm[3][2];
        float t4 = sm[0][3] + sm[1][3] + sm[2][3] + sm[3][3];
        float hinge = fmaxf(t1 - t2, 0.0f) + fmaxf(t4 - t3, 0.0f);
        atomicAdd(acc, hinge);
    }
}

// ---------------------------------------------------------------------------
// Kernel 3: sum of squares of exemplars (for the norm==0 gate). ws[2].
// ---------------------------------------------------------------------------
__global__ __launch_bounds__(256) void sumsq_kernel(const float* __restrict__ ex,
                                                    float* __restrict__ acc) {
    const size_t n4 = (size_t)C * D / 4;     // 2,560,000 float4
    const float4* p = (const float4*)ex;
    float s = 0.0f;
    for (size_t i = (size_t)blockIdx.x * 256 + threadIdx.x; i < n4;
         i += (size_t)gridDim.x * 256) {
        float4 v = p[i];
        s += v.x * v.x + v.y * v.y + v.z * v.z + v.w * v.w;
    }
    #pragma unroll
    for (int off = 1; off < 64; off <<= 1) s += __shfl_xor(s, off, 64);
    if ((threadIdx.x & 63) == 0) atomicAdd(acc, s);
}

// ---------------------------------------------------------------------------
// Kernel 4: finalize -> d_out[3] = {loss_total, loss_softmax, loss_center}
// ---------------------------------------------------------------------------
__global__ void finalize_kernel(const float* __restrict__ ws, float* __restrict__ out) {
    float ce = ws[0] * (1.0f / (2.0f * B));
    float center = ws[1];
    float sumsq = ws[2];
    float total = (sumsq == 0.0f) ? ce : ce + LAMBDA_F * center;
    out[0] = total;
    out[1] = ce;
    out[2] = center;
}

extern "C" void kernel_launch(void* const* d_in, const int* in_sizes, int n_in,
                              void* d_out, int out_size, void* d_ws, size_t ws_size,
                              hipStream_t stream) {
    const float* anchor    = (const float*)d_in[0];
    const float* negative  = (const float*)d_in[1];
    const float* outputs   = (const float*)d_in[2];
    const int*   labels_a  = (const int*)d_in[3];
    const int*   labels_n  = (const int*)d_in[4];
    const float* exemplars = (const float*)d_in[5];
    float* out = (float*)d_out;
    float* ws  = (float*)d_ws;

    hipMemsetAsync(d_ws, 0, 3 * sizeof(float), stream);

    ce_kernel<<<2 * B, 256, 0, stream>>>(outputs, labels_a, labels_n, ws + 0);
    center_kernel<<<B, 256, 0, stream>>>(anchor, negative, exemplars,
                                         labels_a, labels_n, ws + 1);
    sumsq_kernel<<<2048, 256, 0, stream>>>(exemplars, ws + 2);
    finalize_kernel<<<1, 1, 0, stream>>>(ws, out);
}

// Round 2
// 97.301 us; speedup vs baseline: 3.0999x; 3.0999x over previous
//
#include <hip/hip_runtime.h>
#include <math.h>

// Problem constants (fixed by setup_inputs)
#define B   4096
#define D   1024
#define C   10000
#define SCALE_F  30.0f
#define LAMBDA_F 0.1f
#define EPS_F    1e-6f
#define LOG2E    1.4426950408889634f
#define NEG_BIG  (-3.402823466e38f)

// ws layout (floats):
//   [0        .. 2B-1 ]  ce partials        (8192)
//   [2B       .. 3B-1 ]  center partials    (4096)
//   [3B       .. 3B+2047] sumsq partials    (2048)
#define CE_OFF   0
#define CEN_OFF  (2 * B)
#define SQ_OFF   (3 * B)
#define SQ_BLOCKS 2048

// Combine two (max, sum-of-exp) partial logsumexp states.
__device__ inline void lse_combine(float& m, float& s, float m2, float s2) {
    float mn = fmaxf(m, m2);
    s = s * exp2f((m - mn) * LOG2E) + s2 * exp2f((m2 - mn) * LOG2E);
    m = mn;
}

// ---------------------------------------------------------------------------
// Kernel 1: cross-entropy rows.  One block per row of outputs [2B, C].
// part[row] = logsumexp(SCALE*row) - SCALE*row[label]
// ---------------------------------------------------------------------------
__global__ __launch_bounds__(256) void ce_kernel(const float* __restrict__ outputs,
                                                 const int* __restrict__ labels_a,
                                                 const int* __restrict__ labels_n,
                                                 float* __restrict__ part) {
    const int row = blockIdx.x;          // 0 .. 2B-1
    const int tid = threadIdx.x;
    const int lab = (row < B) ? labels_a[row] : labels_n[row - B];

    const float* rowbase = outputs + (size_t)row * C;
    const float4* rowp = (const float4*)rowbase;
    const float target = rowbase[lab];   // broadcast load

    float m = NEG_BIG, s = 0.0f;
    #pragma unroll 2
    for (int i = tid; i < C / 4; i += 256) {
        float4 v = rowp[i];
        float y0 = SCALE_F * v.x, y1 = SCALE_F * v.y;
        float y2 = SCALE_F * v.z, y3 = SCALE_F * v.w;
        float mloc = fmaxf(fmaxf(y0, y1), fmaxf(y2, y3));
        float mn = fmaxf(m, mloc);
        float sc = exp2f((m - mn) * LOG2E);
        float e = exp2f((y0 - mn) * LOG2E) + exp2f((y1 - mn) * LOG2E)
                + exp2f((y2 - mn) * LOG2E) + exp2f((y3 - mn) * LOG2E);
        s = fmaf(s, sc, e);
        m = mn;
    }

    #pragma unroll
    for (int off = 1; off < 64; off <<= 1) {
        float m2 = __shfl_xor(m, off, 64);
        float s2 = __shfl_xor(s, off, 64);
        lse_combine(m, s, m2, s2);
    }

    __shared__ float sm_m[4], sm_s[4];
    const int wid = tid >> 6, lane = tid & 63;
    if (lane == 0) { sm_m[wid] = m; sm_s[wid] = s; }
    __syncthreads();
    if (tid == 0) {
        float M = sm_m[0], S = sm_s[0];
        lse_combine(M, S, sm_m[1], sm_s[1]);
        lse_combine(M, S, sm_m[2], sm_s[2]);
        lse_combine(M, S, sm_m[3], sm_s[3]);
        float lse = M + log2f(S) / LOG2E;
        part[row] = lse - SCALE_F * target;
    }
}

// ---------------------------------------------------------------------------
// Kernel 2: exemplar-center term.  One block per batch row.
// part[row] = relu(d_ref1 - d_neg1) + relu(d_neg2 - d_ref2)
// ---------------------------------------------------------------------------
__global__ __launch_bounds__(256) void center_kernel(const float* __restrict__ anchor,
                                                     const float* __restrict__ negative,
                                                     const float* __restrict__ exemplars,
                                                     const int* __restrict__ labels_a,
                                                     const int* __restrict__ labels_n,
                                                     float* __restrict__ part) {
    const int row = blockIdx.x;          // 0 .. B-1
    const int tid = threadIdx.x;         // D/4 = 256 float4 per row
    const int la = labels_a[row];
    const int ln = labels_n[row];

    float4 a  = ((const float4*)(anchor    + (size_t)row * D))[tid];
    float4 n  = ((const float4*)(negative  + (size_t)row * D))[tid];
    float4 ea = ((const float4*)(exemplars + (size_t)la  * D))[tid];
    float4 en = ((const float4*)(exemplars + (size_t)ln  * D))[tid];

    // s1=d_ref1(a,ea) s2=d_neg1(n,ea) s3=d_ref2(a,en) s4=d_neg2(n,en)
    float s1 = fabsf(a.x - ea.x + EPS_F) + fabsf(a.y - ea.y + EPS_F)
             + fabsf(a.z - ea.z + EPS_F) + fabsf(a.w - ea.w + EPS_F);
    float s2 = fabsf(n.x - ea.x + EPS_F) + fabsf(n.y - ea.y + EPS_F)
             + fabsf(n.z - ea.z + EPS_F) + fabsf(n.w - ea.w + EPS_F);
    float s3 = fabsf(a.x - en.x + EPS_F) + fabsf(a.y - en.y + EPS_F)
             + fabsf(a.z - en.z + EPS_F) + fabsf(a.w - en.w + EPS_F);
    float s4 = fabsf(n.x - en.x + EPS_F) + fabsf(n.y - en.y + EPS_F)
             + fabsf(n.z - en.z + EPS_F) + fabsf(n.w - en.w + EPS_F);

    #pragma unroll
    for (int off = 1; off < 64; off <<= 1) {
        s1 += __shfl_xor(s1, off, 64);
        s2 += __shfl_xor(s2, off, 64);
        s3 += __shfl_xor(s3, off, 64);
        s4 += __shfl_xor(s4, off, 64);
    }

    __shared__ float sm[4][4];
    const int wid = tid >> 6, lane = tid & 63;
    if (lane == 0) { sm[wid][0] = s1; sm[wid][1] = s2; sm[wid][2] = s3; sm[wid][3] = s4; }
    __syncthreads();
    if (tid == 0) {
        float t1 = sm[0][0] + sm[1][0] + sm[2][0] + sm[3][0];
        float t2 = sm[0][1] + sm[1][1] + sm[2][1] + sm[3][1];
        float t3 = sm[0][2] + sm[1][2] + sm[2][2] + sm[3][2];
        float t4 = sm[0][3] + sm[1][3] + sm[2][3] + sm[3][3];
        part[row] = fmaxf(t1 - t2, 0.0f) + fmaxf(t4 - t3, 0.0f);
    }
}

// ---------------------------------------------------------------------------
// Kernel 3: sum of squares of exemplars (norm==0 gate). part[blk].
// ---------------------------------------------------------------------------
__global__ __launch_bounds__(256) void sumsq_kernel(const float* __restrict__ ex,
                                                    float* __restrict__ part) {
    const size_t n4 = (size_t)C * D / 4;     // 2,560,000 float4
    const float4* p = (const float4*)ex;
    float s = 0.0f;
    for (size_t i = (size_t)blockIdx.x * 256 + threadIdx.x; i < n4;
         i += (size_t)SQ_BLOCKS * 256) {
        float4 v = p[i];
        s += v.x * v.x + v.y * v.y + v.z * v.z + v.w * v.w;
    }
    #pragma unroll
    for (int off = 1; off < 64; off <<= 1) s += __shfl_xor(s, off, 64);

    __shared__ float sm[4];
    const int wid = threadIdx.x >> 6, lane = threadIdx.x & 63;
    if (lane == 0) sm[wid] = s;
    __syncthreads();
    if (threadIdx.x == 0) part[blockIdx.x] = sm[0] + sm[1] + sm[2] + sm[3];
}

// ---------------------------------------------------------------------------
// Kernel 4: finalize — reduce all partials, write d_out[3].
// ---------------------------------------------------------------------------
__global__ __launch_bounds__(256) void finalize_kernel(const float* __restrict__ ws,
                                                       float* __restrict__ out) {
    const int tid = threadIdx.x;
    float ce = 0.0f, cen = 0.0f, sq = 0.0f;
    for (int i = tid; i < 2 * B; i += 256)      ce  += ws[CE_OFF  + i];
    for (int i = tid; i < B; i += 256)          cen += ws[CEN_OFF + i];
    for (int i = tid; i < SQ_BLOCKS; i += 256)  sq  += ws[SQ_OFF  + i];

    #pragma unroll
    for (int off = 1; off < 64; off <<= 1) {
        ce  += __shfl_xor(ce,  off, 64);
        cen += __shfl_xor(cen, off, 64);
        sq  += __shfl_xor(sq,  off, 64);
    }

    __shared__ float sm[4][3];
    const int wid = tid >> 6, lane = tid & 63;
    if (lane == 0) { sm[wid][0] = ce; sm[wid][1] = cen; sm[wid][2] = sq; }
    __syncthreads();
    if (tid == 0) {
        float CE  = (sm[0][0] + sm[1][0] + sm[2][0] + sm[3][0]) * (1.0f / (2.0f * B));
        float CEN =  sm[0][1] + sm[1][1] + sm[2][1] + sm[3][1];
        float SQ  =  sm[0][2] + sm[1][2] + sm[2][2] + sm[3][2];
        float total = (SQ == 0.0f) ? CE : CE + LAMBDA_F * CEN;
        out[0] = total;
        out[1] = CE;
        out[2] = CEN;
    }
}

extern "C" void kernel_launch(void* const* d_in, const int* in_sizes, int n_in,
                              void* d_out, int out_size, void* d_ws, size_t ws_size,
                              hipStream_t stream) {
    const float* anchor    = (const float*)d_in[0];
    const float* negative  = (const float*)d_in[1];
    const float* outputs   = (const float*)d_in[2];
    const int*   labels_a  = (const int*)d_in[3];
    const int*   labels_n  = (const int*)d_in[4];
    const float* exemplars = (const float*)d_in[5];
    float* out = (float*)d_out;
    float* ws  = (float*)d_ws;

    ce_kernel<<<2 * B, 256, 0, stream>>>(outputs, labels_a, labels_n, ws + CE_OFF);
    center_kernel<<<B, 256, 0, stream>>>(anchor, negative, exemplars,
                                         labels_a, labels_n, ws + CEN_OFF);
    sumsq_kernel<<<SQ_BLOCKS, 256, 0, stream>>>(exemplars, ws + SQ_OFF);
    finalize_kernel<<<1, 256, 0, stream>>>(ws, out);
}

// Round 3
// 88.575 us; speedup vs baseline: 3.4053x; 1.0985x over previous
//
#include <hip/hip_runtime.h>
#include <math.h>

// Problem constants (fixed by setup_inputs)
#define B   4096
#define D   1024
#define C   10000
#define SCALE_F  30.0f
#define LAMBDA_F 0.1f
#define EPS_F    1e-6f
#define LOG2E    1.4426950408889634f
#define NEG_BIG  (-3.402823466e38f)

// ws layout (floats):
//   [0        .. 2B-1   ]  ce partials        (8192)
//   [2B       .. 3B-1   ]  center partials    (4096)
//   [3B       .. 3B+2047]  sumsq partials     (2048)
#define CE_OFF   0
#define CEN_OFF  (2 * B)
#define SQ_OFF   (3 * B)
#define SQ_BLOCKS 2048
#define CE_BLOCKS (2 * B)
#define TOTAL_BLOCKS (CE_BLOCKS + B + SQ_BLOCKS)   // 14336

// Combine two (max, sum-of-exp) partial logsumexp states.
__device__ inline void lse_combine(float& m, float& s, float m2, float s2) {
    float mn = fmaxf(m, m2);
    s = s * exp2f((m - mn) * LOG2E) + s2 * exp2f((m2 - mn) * LOG2E);
    m = mn;
}

// ---------------------------------------------------------------------------
// Fused kernel: block role by blockIdx.x.
//   [0, 2B)            : cross-entropy row (outputs [2B, C])
//   [2B, 3B)           : center-hinge row  (anchor/negative/exemplars, D)
//   [3B, 3B+SQ_BLOCKS) : exemplar sum-of-squares chunk
// ---------------------------------------------------------------------------
__global__ __launch_bounds__(256) void fused_kernel(const float* __restrict__ outputs,
                                                    const float* __restrict__ anchor,
                                                    const float* __restrict__ negative,
                                                    const float* __restrict__ exemplars,
                                                    const int* __restrict__ labels_a,
                                                    const int* __restrict__ labels_n,
                                                    float* __restrict__ ws) {
    const int blk = blockIdx.x;
    const int tid = threadIdx.x;
    const int wid = tid >> 6, lane = tid & 63;

    if (blk < CE_BLOCKS) {
        // ---------------- cross-entropy row ----------------
        const int row = blk;
        const int lab = (row < B) ? labels_a[row] : labels_n[row - B];
        const float* rowbase = outputs + (size_t)row * C;
        const float4* rowp = (const float4*)rowbase;
        const float target = rowbase[lab];   // broadcast load

        float m = NEG_BIG, s = 0.0f;
        #pragma unroll 2
        for (int i = tid; i < C / 4; i += 256) {
            float4 v = rowp[i];
            float y0 = SCALE_F * v.x, y1 = SCALE_F * v.y;
            float y2 = SCALE_F * v.z, y3 = SCALE_F * v.w;
            float mloc = fmaxf(fmaxf(y0, y1), fmaxf(y2, y3));
            float mn = fmaxf(m, mloc);
            float sc = exp2f((m - mn) * LOG2E);
            float e = exp2f((y0 - mn) * LOG2E) + exp2f((y1 - mn) * LOG2E)
                    + exp2f((y2 - mn) * LOG2E) + exp2f((y3 - mn) * LOG2E);
            s = fmaf(s, sc, e);
            m = mn;
        }

        #pragma unroll
        for (int off = 1; off < 64; off <<= 1) {
            float m2 = __shfl_xor(m, off, 64);
            float s2 = __shfl_xor(s, off, 64);
            lse_combine(m, s, m2, s2);
        }

        __shared__ float sm_m[4], sm_s[4];
        if (lane == 0) { sm_m[wid] = m; sm_s[wid] = s; }
        __syncthreads();
        if (tid == 0) {
            float M = sm_m[0], S = sm_s[0];
            lse_combine(M, S, sm_m[1], sm_s[1]);
            lse_combine(M, S, sm_m[2], sm_s[2]);
            lse_combine(M, S, sm_m[3], sm_s[3]);
            float lse = M + log2f(S) / LOG2E;
            ws[CE_OFF + row] = lse - SCALE_F * target;
        }
    } else if (blk < CE_BLOCKS + B) {
        // ---------------- center-hinge row ----------------
        const int row = blk - CE_BLOCKS;
        const int la = labels_a[row];
        const int ln = labels_n[row];

        float4 a  = ((const float4*)(anchor    + (size_t)row * D))[tid];
        float4 n  = ((const float4*)(negative  + (size_t)row * D))[tid];
        float4 ea = ((const float4*)(exemplars + (size_t)la  * D))[tid];
        float4 en = ((const float4*)(exemplars + (size_t)ln  * D))[tid];

        // s1=d_ref1(a,ea) s2=d_neg1(n,ea) s3=d_ref2(a,en) s4=d_neg2(n,en)
        float s1 = fabsf(a.x - ea.x + EPS_F) + fabsf(a.y - ea.y + EPS_F)
                 + fabsf(a.z - ea.z + EPS_F) + fabsf(a.w - ea.w + EPS_F);
        float s2 = fabsf(n.x - ea.x + EPS_F) + fabsf(n.y - ea.y + EPS_F)
                 + fabsf(n.z - ea.z + EPS_F) + fabsf(n.w - ea.w + EPS_F);
        float s3 = fabsf(a.x - en.x + EPS_F) + fabsf(a.y - en.y + EPS_F)
                 + fabsf(a.z - en.z + EPS_F) + fabsf(a.w - en.w + EPS_F);
        float s4 = fabsf(n.x - en.x + EPS_F) + fabsf(n.y - en.y + EPS_F)
                 + fabsf(n.z - en.z + EPS_F) + fabsf(n.w - en.w + EPS_F);

        #pragma unroll
        for (int off = 1; off < 64; off <<= 1) {
            s1 += __shfl_xor(s1, off, 64);
            s2 += __shfl_xor(s2, off, 64);
            s3 += __shfl_xor(s3, off, 64);
            s4 += __shfl_xor(s4, off, 64);
        }

        __shared__ float sm[4][4];
        if (lane == 0) { sm[wid][0] = s1; sm[wid][1] = s2; sm[wid][2] = s3; sm[wid][3] = s4; }
        __syncthreads();
        if (tid == 0) {
            float t1 = sm[0][0] + sm[1][0] + sm[2][0] + sm[3][0];
            float t2 = sm[0][1] + sm[1][1] + sm[2][1] + sm[3][1];
            float t3 = sm[0][2] + sm[1][2] + sm[2][2] + sm[3][2];
            float t4 = sm[0][3] + sm[1][3] + sm[2][3] + sm[3][3];
            ws[CEN_OFF + row] = fmaxf(t1 - t2, 0.0f) + fmaxf(t4 - t3, 0.0f);
        }
    } else {
        // ---------------- exemplar sum-of-squares chunk ----------------
        const int chunk = blk - (CE_BLOCKS + B);
        const size_t n4 = (size_t)C * D / 4;     // 2,560,000 float4
        const float4* p = (const float4*)exemplars;
        float s = 0.0f;
        for (size_t i = (size_t)chunk * 256 + tid; i < n4;
             i += (size_t)SQ_BLOCKS * 256) {
            float4 v = p[i];
            s += v.x * v.x + v.y * v.y + v.z * v.z + v.w * v.w;
        }
        #pragma unroll
        for (int off = 1; off < 64; off <<= 1) s += __shfl_xor(s, off, 64);

        __shared__ float smq[4];
        if (lane == 0) smq[wid] = s;
        __syncthreads();
        if (tid == 0) ws[SQ_OFF + chunk] = smq[0] + smq[1] + smq[2] + smq[3];
    }
}

// ---------------------------------------------------------------------------
// Finalize — reduce all partials, write d_out[3].
// ---------------------------------------------------------------------------
__global__ __launch_bounds__(256) void finalize_kernel(const float* __restrict__ ws,
                                                       float* __restrict__ out) {
    const int tid = threadIdx.x;
    float ce = 0.0f, cen = 0.0f, sq = 0.0f;
    for (int i = tid; i < 2 * B; i += 256)      ce  += ws[CE_OFF  + i];
    for (int i = tid; i < B; i += 256)          cen += ws[CEN_OFF + i];
    for (int i = tid; i < SQ_BLOCKS; i += 256)  sq  += ws[SQ_OFF  + i];

    #pragma unroll
    for (int off = 1; off < 64; off <<= 1) {
        ce  += __shfl_xor(ce,  off, 64);
        cen += __shfl_xor(cen, off, 64);
        sq  += __shfl_xor(sq,  off, 64);
    }

    __shared__ float sm[4][3];
    const int wid = tid >> 6, lane = tid & 63;
    if (lane == 0) { sm[wid][0] = ce; sm[wid][1] = cen; sm[wid][2] = sq; }
    __syncthreads();
    if (tid == 0) {
        float CE  = (sm[0][0] + sm[1][0] + sm[2][0] + sm[3][0]) * (1.0f / (2.0f * B));
        float CEN =  sm[0][1] + sm[1][1] + sm[2][1] + sm[3][1];
        float SQ  =  sm[0][2] + sm[1][2] + sm[2][2] + sm[3][2];
        float total = (SQ == 0.0f) ? CE : CE + LAMBDA_F * CEN;
        out[0] = total;
        out[1] = CE;
        out[2] = CEN;
    }
}

extern "C" void kernel_launch(void* const* d_in, const int* in_sizes, int n_in,
                              void* d_out, int out_size, void* d_ws, size_t ws_size,
                              hipStream_t stream) {
    const float* anchor    = (const float*)d_in[0];
    const float* negative  = (const float*)d_in[1];
    const float* outputs   = (const float*)d_in[2];
    const int*   labels_a  = (const int*)d_in[3];
    const int*   labels_n  = (const int*)d_in[4];
    const float* exemplars = (const float*)d_in[5];
    float* out = (float*)d_out;
    float* ws  = (float*)d_ws;

    fused_kernel<<<TOTAL_BLOCKS, 256, 0, stream>>>(outputs, anchor, negative,
                                                   exemplars, labels_a, labels_n, ws);
    finalize_kernel<<<1, 256, 0, stream>>>(ws, out);
}